// Round 3
// baseline (350.623 us; speedup 1.0000x reference)
//
#include <hip/hip_runtime.h>
#include <stdint.h>

// Problem constants
#define IN_F   4096
#define OUT_F  4096
#define M_ROWS 8192      // 4 * 2048
#define KT     (IN_F / 64)   // 64 K-tiles of BK=64

typedef __attribute__((ext_vector_type(8))) short  bf16x8;
typedef __attribute__((ext_vector_type(4))) float  f32x4;

__device__ __forceinline__ short f2bf(float f) {
    union { float f; uint32_t u; } v; v.f = f;
    uint32_t r = v.u + 0x7FFFu + ((v.u >> 16) & 1u);
    return (short)(r >> 16);
}

__device__ __forceinline__ void load_lds16(const void* gsrc, void* lds) {
    __builtin_amdgcn_global_load_lds(
        (const __attribute__((address_space(1))) uint32_t*)gsrc,
        (__attribute__((address_space(3))) uint32_t*)lds,
        16, 0, 0);
}

// ============================================================================
// Kernel 1: GPTQ dequant -> W^T bf16 [OUT_F][IN_F]
// ============================================================================
__global__ void dequant_wt_kernel(const int* __restrict__ qweight,
                                  const int* __restrict__ qzeros,
                                  const float* __restrict__ scales,
                                  short* __restrict__ wt)
{
    int t  = blockIdx.x * blockDim.x + threadIdx.x;
    int n  = t >> 9;
    int kw = t & 511;
    int g  = kw >> 4;

    float s = scales[g * OUT_F + n];
    uint32_t zw = (uint32_t)qzeros[g * (OUT_F / 8) + (n >> 3)];
    float z1 = (float)((zw >> (4 * (n & 7))) & 0xFu) + 1.0f;
    uint32_t q = (uint32_t)qweight[kw * OUT_F + n];

    bf16x8 out;
#pragma unroll
    for (int i = 0; i < 8; ++i) {
        float w = s * ((float)((q >> (4 * i)) & 0xFu) - z1);
        out[i] = f2bf(w);
    }
    *reinterpret_cast<bf16x8*>(&wt[(size_t)n * IN_F + kw * 8]) = out;
}

// ============================================================================
// Kernel 2: X fp32 -> bf16 prepass
// ============================================================================
__global__ void xconv_kernel(const float* __restrict__ x, short* __restrict__ xb)
{
    int t = blockIdx.x * blockDim.x + threadIdx.x;
    const float4* src = reinterpret_cast<const float4*>(x) + (size_t)t * 2;
    float4 a = src[0], b = src[1];
    bf16x8 h;
    h[0] = f2bf(a.x); h[1] = f2bf(a.y); h[2] = f2bf(a.z); h[3] = f2bf(a.w);
    h[4] = f2bf(b.x); h[5] = f2bf(b.y); h[6] = f2bf(b.z); h[7] = f2bf(b.w);
    reinterpret_cast<bf16x8*>(xb)[t] = h;
}

// ============================================================================
// Kernel 3: 256x256 phase-split GEMM with COUNTED vmcnt pipeline (T3+T4)
//   LDS: A x3 slots (96KB) + B x2 slots (64KB) = 160KB (full CU budget)
//   Per tile t: issue B(t+1) at q0, A(t+2) at q2.
//   Invariant at tile top: outstanding = A(t+1) (4 loads).
//   End-of-tile wait: vmcnt(4)  (A(t+1)+B(t+1) landed; A(t+2) stays in flight)
//   T2 swizzle unchanged from r2 (measured 0 bank conflicts).
// ============================================================================
#define A_SLOT 32768   // bytes: 256 rows x 64 k x 2B
#define B_SLOT 32768

__global__ __launch_bounds__(512, 1) void gemm8_kernel(
    const short* __restrict__ Xb,   // [M_ROWS][IN_F] bf16
    const short* __restrict__ WT,   // [OUT_F][IN_F] bf16
    float* __restrict__ C)          // [M_ROWS][OUT_F]
{
    __shared__ short AsBuf[3 * 256 * 64];   // 96 KB
    __shared__ short BsBuf[2 * 256 * 64];   // 64 KB
    char* const Abase = (char*)AsBuf;
    char* const Bbase = (char*)BsBuf;

    const int tid  = threadIdx.x;
    const int lane = tid & 63;
    const int wid  = tid >> 6;     // 0..7
    const int wr   = wid >> 2;     // 0..1  (M half)
    const int wc   = wid & 3;      // 0..3  (N quarter)

    const int row0 = blockIdx.y * 256;
    const int col0 = blockIdx.x * 256;

    // ---- staging geometry (identical to r2): load L covers slot bytes
    //      [L*8192 + tid*16, +16); source col pre-swizzled (rule 21)
    const int rL0 = tid >> 3;
    const int csw = ((tid & 7) << 3) ^ ((rL0 & 7) << 3);
    const short* gA[4]; const short* gB[4]; int dOff[4];
#pragma unroll
    for (int L = 0; L < 4; ++L) {
        const int r = L * 64 + rL0;
        gA[L] = Xb + (size_t)(row0 + r) * IN_F + csw;
        gB[L] = WT + (size_t)(col0 + r) * IN_F + csw;
        dOff[L] = L * 8192 + tid * 16;
    }

    // ---- read geometry (identical to r2)
    const int frow = lane & 15;
    const int k0   = ((lane >> 4) << 4) ^ ((frow & 7) << 4);

    f32x4 acc[8][4] = {};

    // ---- prologue: issue A(0), B(0), A(1); wait A0+B0; leave A1 in flight
#pragma unroll
    for (int L = 0; L < 4; ++L) load_lds16(gA[L],      Abase + 0 * A_SLOT + dOff[L]);
#pragma unroll
    for (int L = 0; L < 4; ++L) load_lds16(gB[L],      Bbase + 0 * B_SLOT + dOff[L]);
#pragma unroll
    for (int L = 0; L < 4; ++L) load_lds16(gA[L] + 64, Abase + 1 * A_SLOT + dOff[L]);
    asm volatile("s_waitcnt vmcnt(4)" ::: "memory");
    __builtin_amdgcn_s_barrier();

    int sA = 0;   // A slot of tile t   (t % 3)
    int sB = 0;   // B slot of tile t   (t & 1)

    for (int t = 0; t < KT; ++t) {
        char* Ab = Abase + sA * A_SLOT;
        char* Bb = Bbase + sB * B_SLOT;
        const int sA2 = (sA >= 1) ? sA - 1 : 2;       // (t+2) % 3
        char* An = Abase + sA2 * A_SLOT;
        char* Bn = Bbase + (sB ^ 1) * B_SLOT;
        const bool pfB = (t + 1 < KT);
        const bool pfA = (t + 2 < KT);

#pragma unroll
        for (int q = 0; q < 4; ++q) {      // 4 phases: C-quadrants
            const int mq = q >> 1, nq = q & 1;

            // -- ds reads for this quadrant (12 x ds_read_b128)
            bf16x8 af[4][2]; bf16x8 bfr[2][2];
#pragma unroll
            for (int m = 0; m < 4; ++m) {
                const int r = wr * 128 + (mq * 4 + m) * 16 + frow;
                char* base = Ab + r * 128;
                af[m][0] = *reinterpret_cast<const bf16x8*>(base + k0);
                af[m][1] = *reinterpret_cast<const bf16x8*>(base + (k0 ^ 64));
            }
#pragma unroll
            for (int n = 0; n < 2; ++n) {
                const int r = wc * 64 + (nq * 2 + n) * 16 + frow;
                char* base = Bb + r * 128;
                bfr[n][0] = *reinterpret_cast<const bf16x8*>(base + k0);
                bfr[n][1] = *reinterpret_cast<const bf16x8*>(base + (k0 ^ 64));
            }

            // -- staging: B(t+1) at q0, A(t+2) at q2  (B older than A in queue)
            if (q == 0 && pfB) {
#pragma unroll
                for (int L = 0; L < 4; ++L)
                    load_lds16(gB[L] + (size_t)(t + 1) * 64, Bn + dOff[L]);
            }
            if (q == 2 && pfA) {
#pragma unroll
                for (int L = 0; L < 4; ++L)
                    load_lds16(gA[L] + (size_t)(t + 2) * 64, An + dOff[L]);
            }

            __builtin_amdgcn_s_barrier();
            asm volatile("s_waitcnt lgkmcnt(0)" ::: "memory");
            __builtin_amdgcn_sched_barrier(0);   // rule 18

            __builtin_amdgcn_s_setprio(1);
#pragma unroll
            for (int m = 0; m < 4; ++m)
#pragma unroll
                for (int n = 0; n < 2; ++n) {
                    acc[mq * 4 + m][nq * 2 + n] =
                        __builtin_amdgcn_mfma_f32_16x16x32_bf16(
                            af[m][0], bfr[n][0], acc[mq * 4 + m][nq * 2 + n], 0, 0, 0);
                    acc[mq * 4 + m][nq * 2 + n] =
                        __builtin_amdgcn_mfma_f32_16x16x32_bf16(
                            af[m][1], bfr[n][1], acc[mq * 4 + m][nq * 2 + n], 0, 0, 0);
                }
            __builtin_amdgcn_s_setprio(0);

            if (q == 3) {
                // counted wait: A(t+1), B(t+1) landed; A(t+2) stays in flight
                if (t < KT - 2)       asm volatile("s_waitcnt vmcnt(4)" ::: "memory");
                else if (t == KT - 2) asm volatile("s_waitcnt vmcnt(0)" ::: "memory");
            }
            __builtin_amdgcn_s_barrier();
        }

        sA = (sA < 2) ? sA + 1 : 0;
        sB ^= 1;
    }

    // ---- epilogue: C/D layout col=lane&15, row=(lane>>4)*4+reg (verified)
    const int crow = (lane >> 4) * 4;
    const int ccol = lane & 15;
#pragma unroll
    for (int fm = 0; fm < 8; ++fm)
#pragma unroll
        for (int fn = 0; fn < 4; ++fn)
#pragma unroll
            for (int r = 0; r < 4; ++r) {
                const int row = row0 + wr * 128 + fm * 16 + crow + r;
                const int col = col0 + wc * 64 + fn * 16 + ccol;
                C[(size_t)row * OUT_F + col] = acc[fm][fn][r];
            }
}

// ============================================================================
// Fallback GEMM (round-1, verified): used only if ws too small for Xb
// ============================================================================
#define BM 128
#define BN 128
#define BK 64

__global__ __launch_bounds__(256, 2) void gemm_x_wt_kernel(
    const float* __restrict__ X,
    const short* __restrict__ WT,
    float* __restrict__ C)
{
    __shared__ short As2[BM * BK];
    __shared__ short Bs2[BN * BK];

    const int bn = blockIdx.x;
    const int bm = blockIdx.y;
    const int tid  = threadIdx.x;
    const int lane = tid & 63;
    const int wid  = tid >> 6;
    const int wr   = wid >> 1;
    const int wc   = wid & 1;

    const int row0 = bm * BM;
    const int col0 = bn * BN;
    const int frow = lane & 15;
    const int fk   = (lane >> 4) * 8;

    f32x4 acc[4][4] = {};

    for (int kt = 0; kt < IN_F / BK; ++kt) {
        float4 a0[4], a1[4];
#pragma unroll
        for (int j = 0; j < 4; ++j) {
            const int flat = (j * 256 + tid) * 8;
            const int r = flat >> 6;
            const int c = flat & (BK - 1);
            const float* src = X + (size_t)(row0 + r) * IN_F + kt * BK + c;
            a0[j] = *reinterpret_cast<const float4*>(src);
            a1[j] = *reinterpret_cast<const float4*>(src + 4);
        }
        __syncthreads();
#pragma unroll
        for (int j = 0; j < 4; ++j) {
            const int flat = (j * 256 + tid) * 8;
            const int r = flat >> 6;
            const int c = flat & (BK - 1);
            load_lds16(WT + (size_t)(col0 + r) * IN_F + kt * BK + c, &Bs2[flat]);
        }
#pragma unroll
        for (int j = 0; j < 4; ++j) {
            const int flat = (j * 256 + tid) * 8;
            bf16x8 h;
            h[0] = f2bf(a0[j].x); h[1] = f2bf(a0[j].y);
            h[2] = f2bf(a0[j].z); h[3] = f2bf(a0[j].w);
            h[4] = f2bf(a1[j].x); h[5] = f2bf(a1[j].y);
            h[6] = f2bf(a1[j].z); h[7] = f2bf(a1[j].w);
            *reinterpret_cast<bf16x8*>(&As2[flat]) = h;
        }
        __syncthreads();
#pragma unroll
        for (int s = 0; s < 2; ++s) {
            bf16x8 af[4], bfr[4];
#pragma unroll
            for (int m = 0; m < 4; ++m) {
                const int row = wr * 64 + m * 16 + frow;
                af[m] = *reinterpret_cast<const bf16x8*>(&As2[row * BK + s * 32 + fk]);
            }
#pragma unroll
            for (int n = 0; n < 4; ++n) {
                const int col = wc * 64 + n * 16 + frow;
                bfr[n] = *reinterpret_cast<const bf16x8*>(&Bs2[col * BK + s * 32 + fk]);
            }
#pragma unroll
            for (int m = 0; m < 4; ++m)
#pragma unroll
                for (int n = 0; n < 4; ++n)
                    acc[m][n] = __builtin_amdgcn_mfma_f32_16x16x32_bf16(
                        af[m], bfr[n], acc[m][n], 0, 0, 0);
        }
    }

    const int crow = (lane >> 4) * 4;
    const int ccol = lane & 15;
#pragma unroll
    for (int m = 0; m < 4; ++m)
#pragma unroll
        for (int n = 0; n < 4; ++n)
#pragma unroll
            for (int r = 0; r < 4; ++r) {
                const int row = row0 + wr * 64 + m * 16 + crow + r;
                const int col = col0 + wc * 64 + n * 16 + ccol;
                C[(size_t)row * OUT_F + col] = acc[m][n][r];
            }
}

// ============================================================================
extern "C" void kernel_launch(void* const* d_in, const int* in_sizes, int n_in,
                              void* d_out, int out_size, void* d_ws, size_t ws_size,
                              hipStream_t stream) {
    const float* x       = (const float*)d_in[0];
    const int*   qweight = (const int*)  d_in[1];
    const int*   qzeros  = (const int*)  d_in[2];
    const float* scales  = (const float*)d_in[3];
    float*       out     = (float*)d_out;

    const size_t WT_BYTES = (size_t)OUT_F * IN_F * 2;   // 33.5 MB
    const size_t XB_BYTES = (size_t)M_ROWS * IN_F * 2;  // 67.1 MB

    short* wt = (short*)d_ws;

    dequant_wt_kernel<<<(OUT_F * (IN_F / 8)) / 256, 256, 0, stream>>>(
        qweight, qzeros, scales, wt);

    if (ws_size >= WT_BYTES + XB_BYTES) {
        short* xb = (short*)((char*)d_ws + WT_BYTES);
        xconv_kernel<<<(M_ROWS * IN_F / 8) / 256, 256, 0, stream>>>(x, xb);
        dim3 grid(OUT_F / 256, M_ROWS / 256);   // (16, 32)
        gemm8_kernel<<<grid, 512, 0, stream>>>(xb, wt, out);
    } else {
        dim3 grid(OUT_F / BN, M_ROWS / BM);     // (32, 64)
        gemm_x_wt_kernel<<<grid, 256, 0, stream>>>(x, wt, out);
    }
}

// Round 4
// 272.453 us; speedup vs baseline: 1.2869x; 1.2869x over previous
//
#include <hip/hip_runtime.h>
#include <stdint.h>

// Problem constants
#define IN_F   4096
#define OUT_F  4096
#define M_ROWS 8192      // 4 * 2048
#define KT     (IN_F / 64)   // 64 K-tiles of BK=64

typedef __attribute__((ext_vector_type(8))) short  bf16x8;
typedef __attribute__((ext_vector_type(4))) float  f32x4;

__device__ __forceinline__ short f2bf(float f) {
    union { float f; uint32_t u; } v; v.f = f;
    uint32_t r = v.u + 0x7FFFu + ((v.u >> 16) & 1u);
    return (short)(r >> 16);
}

__device__ __forceinline__ void load_lds16(const void* gsrc, void* lds) {
    __builtin_amdgcn_global_load_lds(
        (const __attribute__((address_space(1))) uint32_t*)gsrc,
        (__attribute__((address_space(3))) uint32_t*)lds,
        16, 0, 0);
}

// ============================================================================
// Kernel 1: GPTQ dequant -> W^T bf16 [OUT_F][IN_F]
// ============================================================================
__global__ void dequant_wt_kernel(const int* __restrict__ qweight,
                                  const int* __restrict__ qzeros,
                                  const float* __restrict__ scales,
                                  short* __restrict__ wt)
{
    int t  = blockIdx.x * blockDim.x + threadIdx.x;
    int n  = t >> 9;
    int kw = t & 511;
    int g  = kw >> 4;

    float s = scales[g * OUT_F + n];
    uint32_t zw = (uint32_t)qzeros[g * (OUT_F / 8) + (n >> 3)];
    float z1 = (float)((zw >> (4 * (n & 7))) & 0xFu) + 1.0f;
    uint32_t q = (uint32_t)qweight[kw * OUT_F + n];

    bf16x8 out;
#pragma unroll
    for (int i = 0; i < 8; ++i) {
        float w = s * ((float)((q >> (4 * i)) & 0xFu) - z1);
        out[i] = f2bf(w);
    }
    *reinterpret_cast<bf16x8*>(&wt[(size_t)n * IN_F + kw * 8]) = out;
}

// ============================================================================
// Kernel 2: X fp32 -> bf16 prepass
// ============================================================================
__global__ void xconv_kernel(const float* __restrict__ x, short* __restrict__ xb)
{
    int t = blockIdx.x * blockDim.x + threadIdx.x;
    const float4* src = reinterpret_cast<const float4*>(x) + (size_t)t * 2;
    float4 a = src[0], b = src[1];
    bf16x8 h;
    h[0] = f2bf(a.x); h[1] = f2bf(a.y); h[2] = f2bf(a.z); h[3] = f2bf(a.w);
    h[4] = f2bf(b.x); h[5] = f2bf(b.y); h[6] = f2bf(b.z); h[7] = f2bf(b.w);
    reinterpret_cast<bf16x8*>(xb)[t] = h;
}

// ============================================================================
// Kernel 3: 256x256 GEMM — deduped ks-phases, ONE barrier per K-tile
//   LDS: A x3 slots (96KB) + B x2 slots (64KB) = 160KB
//   Per tile t: stage B(t+1), A(t+2); end-of-tile: vmcnt(4) + s_barrier
//   Phase ks (ks=0,1): 12 ds_read_b128 (8 A-frags + 4 B-frags, each read ONCE)
//                      then 32 MFMA (8m x 4n). No intra-tile barriers; compiler
//                      schedules ds_read->MFMA with its own counted lgkm waits.
//   T2 swizzle identical to r2/r3 (measured 0 bank conflicts).
// ============================================================================
#define A_SLOT 32768
#define B_SLOT 32768

__global__ __launch_bounds__(512, 1) void gemm8_kernel(
    const short* __restrict__ Xb,   // [M_ROWS][IN_F] bf16
    const short* __restrict__ WT,   // [OUT_F][IN_F] bf16
    float* __restrict__ C)          // [M_ROWS][OUT_F]
{
    __shared__ short AsBuf[3 * 256 * 64];   // 96 KB
    __shared__ short BsBuf[2 * 256 * 64];   // 64 KB
    char* const Abase = (char*)AsBuf;
    char* const Bbase = (char*)BsBuf;

    const int tid  = threadIdx.x;
    const int lane = tid & 63;
    const int wid  = tid >> 6;     // 0..7
    const int wr   = wid >> 2;     // 0..1  (M half)
    const int wc   = wid & 3;      // 0..3  (N quarter)

    const int row0 = blockIdx.y * 256;
    const int col0 = blockIdx.x * 256;

    // ---- staging geometry (verified r2/r3): load L covers slot bytes
    //      [L*8192 + tid*16, +16); source col pre-swizzled (rule 21)
    const int rL0 = tid >> 3;
    const int csw = ((tid & 7) << 3) ^ ((rL0 & 7) << 3);
    const short* gA[4]; const short* gB[4]; int dOff[4];
#pragma unroll
    for (int L = 0; L < 4; ++L) {
        const int r = L * 64 + rL0;
        gA[L] = Xb + (size_t)(row0 + r) * IN_F + csw;
        gB[L] = WT + (size_t)(col0 + r) * IN_F + csw;
        dOff[L] = L * 8192 + tid * 16;
    }

    // ---- read geometry (verified r2/r3); frag(ks) at byte k0 ^ (ks<<6)
    const int frow = lane & 15;
    const int k0   = ((lane >> 4) << 4) ^ ((frow & 7) << 4);

    f32x4 acc[8][4] = {};

    // ---- prologue: issue A(0), B(0), A(1); wait A0+B0; leave A1 in flight
#pragma unroll
    for (int L = 0; L < 4; ++L) load_lds16(gA[L],      Abase + 0 * A_SLOT + dOff[L]);
#pragma unroll
    for (int L = 0; L < 4; ++L) load_lds16(gB[L],      Bbase + 0 * B_SLOT + dOff[L]);
#pragma unroll
    for (int L = 0; L < 4; ++L) load_lds16(gA[L] + 64, Abase + 1 * A_SLOT + dOff[L]);
    asm volatile("s_waitcnt vmcnt(4)" ::: "memory");
    __builtin_amdgcn_s_barrier();

    int sA = 0;   // A slot of tile t   (t % 3)
    int sB = 0;   // B slot of tile t   (t & 1)

    for (int t = 0; t < KT; ++t) {
        char* Ab = Abase + sA * A_SLOT;
        char* Bb = Bbase + sB * B_SLOT;
        const int sA2 = (sA >= 1) ? sA - 1 : 2;       // (t+2) % 3
        char* An = Abase + sA2 * A_SLOT;
        char* Bn = Bbase + (sB ^ 1) * B_SLOT;
        const bool pfB = (t + 1 < KT);
        const bool pfA = (t + 2 < KT);

#pragma unroll
        for (int ks = 0; ks < 2; ++ks) {
            const int kb = k0 ^ (ks << 6);

            // -- 12 ds_read_b128: every fragment of this K-half, read once
            bf16x8 af[8]; bf16x8 bfr[4];
#pragma unroll
            for (int m = 0; m < 8; ++m) {
                const int r = wr * 128 + m * 16 + frow;
                af[m] = *reinterpret_cast<const bf16x8*>(Ab + r * 128 + kb);
            }
#pragma unroll
            for (int n = 0; n < 4; ++n) {
                const int r = wc * 64 + n * 16 + frow;
                bfr[n] = *reinterpret_cast<const bf16x8*>(Bb + r * 128 + kb);
            }

            // -- staging issued once per tile, overlapped with phase-0 compute
            if (ks == 0) {
                if (pfB) {
#pragma unroll
                    for (int L = 0; L < 4; ++L)
                        load_lds16(gB[L] + (size_t)(t + 1) * 64, Bn + dOff[L]);
                }
                if (pfA) {
#pragma unroll
                    for (int L = 0; L < 4; ++L)
                        load_lds16(gA[L] + (size_t)(t + 2) * 64, An + dOff[L]);
                }
            }

            // -- 32 MFMA; compiler inserts its own counted lgkm waits
            __builtin_amdgcn_s_setprio(1);
#pragma unroll
            for (int m = 0; m < 8; ++m)
#pragma unroll
                for (int n = 0; n < 4; ++n)
                    acc[m][n] = __builtin_amdgcn_mfma_f32_16x16x32_bf16(
                        af[m], bfr[n], acc[m][n], 0, 0, 0);
            __builtin_amdgcn_s_setprio(0);
        }

        // -- ONE barrier per K-tile, counted vmcnt (A(t+2) stays in flight)
        if (t < KT - 2)       asm volatile("s_waitcnt vmcnt(4)" ::: "memory");
        else if (t == KT - 2) asm volatile("s_waitcnt vmcnt(0)" ::: "memory");
        __builtin_amdgcn_s_barrier();

        sA = (sA < 2) ? sA + 1 : 0;
        sB ^= 1;
    }

    // ---- epilogue: C/D layout col=lane&15, row=(lane>>4)*4+reg (verified)
    const int crow = (lane >> 4) * 4;
    const int ccol = lane & 15;
#pragma unroll
    for (int fm = 0; fm < 8; ++fm)
#pragma unroll
        for (int fn = 0; fn < 4; ++fn)
#pragma unroll
            for (int r = 0; r < 4; ++r) {
                const int row = row0 + wr * 128 + fm * 16 + crow + r;
                const int col = col0 + wc * 64 + fn * 16 + ccol;
                C[(size_t)row * OUT_F + col] = acc[fm][fn][r];
            }
}

// ============================================================================
// Fallback GEMM (round-1, verified): used only if ws too small for Xb
// ============================================================================
#define BM 128
#define BN 128
#define BK 64

__global__ __launch_bounds__(256, 2) void gemm_x_wt_kernel(
    const float* __restrict__ X,
    const short* __restrict__ WT,
    float* __restrict__ C)
{
    __shared__ short As2[BM * BK];
    __shared__ short Bs2[BN * BK];

    const int bn = blockIdx.x;
    const int bm = blockIdx.y;
    const int tid  = threadIdx.x;
    const int lane = tid & 63;
    const int wid  = tid >> 6;
    const int wr   = wid >> 1;
    const int wc   = wid & 1;

    const int row0 = bm * BM;
    const int col0 = bn * BN;
    const int frow = lane & 15;
    const int fk   = (lane >> 4) * 8;

    f32x4 acc[4][4] = {};

    for (int kt = 0; kt < IN_F / BK; ++kt) {
        float4 a0[4], a1[4];
#pragma unroll
        for (int j = 0; j < 4; ++j) {
            const int flat = (j * 256 + tid) * 8;
            const int r = flat >> 6;
            const int c = flat & (BK - 1);
            const float* src = X + (size_t)(row0 + r) * IN_F + kt * BK + c;
            a0[j] = *reinterpret_cast<const float4*>(src);
            a1[j] = *reinterpret_cast<const float4*>(src + 4);
        }
        __syncthreads();
#pragma unroll
        for (int j = 0; j < 4; ++j) {
            const int flat = (j * 256 + tid) * 8;
            const int r = flat >> 6;
            const int c = flat & (BK - 1);
            load_lds16(WT + (size_t)(col0 + r) * IN_F + kt * BK + c, &Bs2[flat]);
        }
#pragma unroll
        for (int j = 0; j < 4; ++j) {
            const int flat = (j * 256 + tid) * 8;
            bf16x8 h;
            h[0] = f2bf(a0[j].x); h[1] = f2bf(a0[j].y);
            h[2] = f2bf(a0[j].z); h[3] = f2bf(a0[j].w);
            h[4] = f2bf(a1[j].x); h[5] = f2bf(a1[j].y);
            h[6] = f2bf(a1[j].z); h[7] = f2bf(a1[j].w);
            *reinterpret_cast<bf16x8*>(&As2[flat]) = h;
        }
        __syncthreads();
#pragma unroll
        for (int s = 0; s < 2; ++s) {
            bf16x8 af[4], bfr[4];
#pragma unroll
            for (int m = 0; m < 4; ++m) {
                const int row = wr * 64 + m * 16 + frow;
                af[m] = *reinterpret_cast<const bf16x8*>(&As2[row * BK + s * 32 + fk]);
            }
#pragma unroll
            for (int n = 0; n < 4; ++n) {
                const int col = wc * 64 + n * 16 + frow;
                bfr[n] = *reinterpret_cast<const bf16x8*>(&Bs2[col * BK + s * 32 + fk]);
            }
#pragma unroll
            for (int m = 0; m < 4; ++m)
#pragma unroll
                for (int n = 0; n < 4; ++n)
                    acc[m][n] = __builtin_amdgcn_mfma_f32_16x16x32_bf16(
                        af[m], bfr[n], acc[m][n], 0, 0, 0);
        }
    }

    const int crow = (lane >> 4) * 4;
    const int ccol = lane & 15;
#pragma unroll
    for (int m = 0; m < 4; ++m)
#pragma unroll
        for (int n = 0; n < 4; ++n)
#pragma unroll
            for (int r = 0; r < 4; ++r) {
                const int row = row0 + wr * 64 + m * 16 + crow + r;
                const int col = col0 + wc * 64 + n * 16 + ccol;
                C[(size_t)row * OUT_F + col] = acc[m][n][r];
            }
}

// ============================================================================
extern "C" void kernel_launch(void* const* d_in, const int* in_sizes, int n_in,
                              void* d_out, int out_size, void* d_ws, size_t ws_size,
                              hipStream_t stream) {
    const float* x       = (const float*)d_in[0];
    const int*   qweight = (const int*)  d_in[1];
    const int*   qzeros  = (const int*)  d_in[2];
    const float* scales  = (const float*)d_in[3];
    float*       out     = (float*)d_out;

    const size_t WT_BYTES = (size_t)OUT_F * IN_F * 2;   // 33.5 MB
    const size_t XB_BYTES = (size_t)M_ROWS * IN_F * 2;  // 67.1 MB

    short* wt = (short*)d_ws;

    dequant_wt_kernel<<<(OUT_F * (IN_F / 8)) / 256, 256, 0, stream>>>(
        qweight, qzeros, scales, wt);

    if (ws_size >= WT_BYTES + XB_BYTES) {
        short* xb = (short*)((char*)d_ws + WT_BYTES);
        xconv_kernel<<<(M_ROWS * IN_F / 8) / 256, 256, 0, stream>>>(x, xb);
        dim3 grid(OUT_F / 256, M_ROWS / 256);   // (16, 32)
        gemm8_kernel<<<grid, 512, 0, stream>>>(xb, wt, out);
    } else {
        dim3 grid(OUT_F / BN, M_ROWS / BM);     // (32, 64)
        gemm_x_wt_kernel<<<grid, 256, 0, stream>>>(x, wt, out);
    }
}